// Round 5
// baseline (609.431 us; speedup 1.0000x reference)
//
#include <hip/hip_runtime.h>

#define SEQ   2048
#define BATCH 2
#define DMODEL 1024
#define DFF   4096
#define NHEAD 16
#define HDIM  64
#define NTOK  (BATCH*SEQ)   // 4096

typedef short s8v __attribute__((ext_vector_type(8)));
typedef float f4v __attribute__((ext_vector_type(4)));

__device__ __forceinline__ float b2f(unsigned short u) {
    union { unsigned int i; float f; } v; v.i = ((unsigned int)u) << 16; return v.f;
}
__device__ __forceinline__ unsigned short f2b(float f) {
    union { unsigned int i; float f; } v; v.f = f;
    unsigned int r = v.i + 0x7FFFu + ((v.i >> 16) & 1u);
    return (unsigned short)(r >> 16);
}

__device__ __forceinline__ f4v mfma_bf16(s8v a, s8v b, f4v c) {
    return __builtin_amdgcn_mfma_f32_16x16x32_bf16(a, b, c, 0, 0, 0);
}

__device__ __forceinline__ void gload_lds16(const void* g, void* l) {
    __builtin_amdgcn_global_load_lds(
        (const __attribute__((address_space(1))) unsigned int*)g,
        (__attribute__((address_space(3))) unsigned int*)l, 16, 0, 0);
}

// ---------------- transpose + fp32->bf16: src [R,C] f32 -> dst [C,R] bf16 ----------------
__global__ __launch_bounds__(256) void transpose_w(const float* __restrict__ src,
                                                   unsigned short* __restrict__ dst,
                                                   int R, int C) {
    __shared__ unsigned short tl[64 * 65];
    const int t = threadIdx.x;
    const int br = blockIdx.x, bc = blockIdx.y;
    for (int i = 0; i < 16; i++) {
        int idx = t + 256 * i;
        int r = idx >> 6, c = idx & 63;
        tl[r * 65 + c] = f2b(src[(size_t)(br * 64 + r) * C + bc * 64 + c]);
    }
    __syncthreads();
    for (int i = 0; i < 16; i++) {
        int idx = t + 256 * i;
        int r2 = idx >> 6, c2 = idx & 63;
        dst[(size_t)(bc * 64 + r2) * R + br * 64 + c2] = tl[c2 * 65 + r2];
    }
}

// ---------------- V transpose: qkv V-part [key][d] -> Vt [b][h][d][key] (bf16) ----------------
__global__ __launch_bounds__(256) void transpose_v(const unsigned short* __restrict__ qkv,
                                                   unsigned short* __restrict__ Vt) {
    __shared__ unsigned short tl[64 * 65];
    const int t = threadIdx.x;
    const int kt = blockIdx.x, h = blockIdx.y, b = blockIdx.z;
    const size_t rs = 3 * DMODEL;
    const size_t src0 = (size_t)b * SEQ * rs + 2 * DMODEL + h * HDIM;
    for (int i = 0; i < 16; i++) {
        int idx = t + 256 * i;
        int r = idx >> 6, c = idx & 63;          // r = key row, c = d
        tl[r * 65 + c] = qkv[src0 + (size_t)(kt * 64 + r) * rs + c];
    }
    __syncthreads();
    const size_t dst0 = ((size_t)(b * NHEAD + h)) * HDIM * SEQ;
    for (int i = 0; i < 16; i++) {
        int idx = t + 256 * i;
        int r2 = idx >> 6, c2 = idx & 63;        // r2 = d, c2 = key
        Vt[dst0 + (size_t)r2 * SEQ + kt * 64 + c2] = tl[c2 * 65 + r2];
    }
}

// ---------------- concat qkv bias (fp32) ----------------
__global__ __launch_bounds__(256) void concat_bias(const float* bq, const float* bk,
                                                   const float* bv, float* o) {
    int t = blockIdx.x * 256 + threadIdx.x;
    if (t < 1024) o[t] = bq[t];
    else if (t < 2048) o[t] = bk[t - 1024];
    else if (t < 3072) o[t] = bv[t - 2048];
}

// ---------------- layernorm fp32 in -> bf16 out (torch: ddof=1, eps on std) ----------------
__global__ __launch_bounds__(256) void ln_kernel(const float* __restrict__ x,
                                                 const float* __restrict__ al,
                                                 const float* __restrict__ be,
                                                 unsigned short* __restrict__ o) {
    const int row = blockIdx.x;
    const float* xr = x + (size_t)row * DMODEL;
    float4 u = ((const float4*)xr)[threadIdx.x];
    float v[4] = { u.x, u.y, u.z, u.w };
    float s = v[0] + v[1] + v[2] + v[3];
    float sq = v[0]*v[0] + v[1]*v[1] + v[2]*v[2] + v[3]*v[3];
    for (int off = 32; off; off >>= 1) { s += __shfl_xor(s, off); sq += __shfl_xor(sq, off); }
    __shared__ float red[8];
    int wave = threadIdx.x >> 6, lane = threadIdx.x & 63;
    if (!lane) { red[wave] = s; red[4 + wave] = sq; }
    __syncthreads();
    s = red[0] + red[1] + red[2] + red[3];
    sq = red[4] + red[5] + red[6] + red[7];
    float mean = s * (1.f / DMODEL);
    float var = (sq - (float)DMODEL * mean * mean) * (1.f / (DMODEL - 1));
    var = var < 0.f ? 0.f : var;
    float inv = al[0] / (sqrtf(var) + 1e-6f);
    float bt = be[0];
    uint2 ou;
    unsigned short r0 = f2b((v[0] - mean) * inv + bt);
    unsigned short r1 = f2b((v[1] - mean) * inv + bt);
    unsigned short r2 = f2b((v[2] - mean) * inv + bt);
    unsigned short r3 = f2b((v[3] - mean) * inv + bt);
    ou.x = (unsigned int)r0 | ((unsigned int)r1 << 16);
    ou.y = (unsigned int)r2 | ((unsigned int)r3 << 16);
    ((uint2*)(o + (size_t)row * DMODEL))[threadIdx.x] = ou;
}

// ---------------- m97-style GEMM: C = [relu](A @ Bt^T + bias) [+ res] ----------------
template<bool RELU, bool RES, typename CT>
__global__ __launch_bounds__(256) void gemm_bt(const unsigned short* __restrict__ A,
                                               const unsigned short* __restrict__ Bt,
                                               const float* __restrict__ bias,
                                               const float* __restrict__ res,
                                               CT* __restrict__ C,
                                               int M, int N, int K) {
    __shared__ __align__(16) unsigned short smA[128 * 32];
    __shared__ __align__(16) unsigned short smB[128 * 32];
    const int t = threadIdx.x;
    const int wave = t >> 6, lane = t & 63;
    const int quad = lane >> 4, l16 = lane & 15;
    const int wm = wave & 1, wn = wave >> 1;
    const int m0 = blockIdx.x * 128, n0 = blockIdx.y * 128;

    f4v acc[4][4] = {};

    const int c0 = t, c1 = t + 256;
    const int rA0 = c0 >> 2, sA0 = c0 & 3;
    const int rA1 = c1 >> 2, sA1 = c1 & 3;

    for (int k0 = 0; k0 < K; k0 += 32) {
        __syncthreads();
        gload_lds16(A  + (size_t)(m0 + rA0) * K + k0 + sA0 * 8, smA + c0 * 8);
        gload_lds16(A  + (size_t)(m0 + rA1) * K + k0 + sA1 * 8, smA + c1 * 8);
        gload_lds16(Bt + (size_t)(n0 + rA0) * K + k0 + sA0 * 8, smB + c0 * 8);
        gload_lds16(Bt + (size_t)(n0 + rA1) * K + k0 + sA1 * 8, smB + c1 * 8);
        __syncthreads();
        s8v a[4], b[4];
        for (int i = 0; i < 4; i++)
            a[i] = *(const s8v*)&smA[(wm * 64 + i * 16 + l16) * 32 + quad * 8];
        for (int i = 0; i < 4; i++)
            b[i] = *(const s8v*)&smB[(wn * 64 + i * 16 + l16) * 32 + quad * 8];
        for (int mi = 0; mi < 4; mi++)
            for (int ni = 0; ni < 4; ni++)
                acc[mi][ni] = mfma_bf16(a[mi], b[ni], acc[mi][ni]);
    }

    for (int mi = 0; mi < 4; mi++) {
        for (int ni = 0; ni < 4; ni++) {
            int col = n0 + wn * 64 + ni * 16 + l16;
            float bv = bias[col];
            for (int r = 0; r < 4; r++) {
                int row = m0 + wm * 64 + mi * 16 + quad * 4 + r;
                float v = acc[mi][ni][r] + bv;
                if (RELU) v = v > 0.f ? v : 0.f;
                if (RES) v += res[(size_t)row * N + col];
                if constexpr (sizeof(CT) == 2)
                    C[(size_t)row * N + col] = f2b(v);
                else
                    C[(size_t)row * N + col] = v;
            }
        }
    }
}

// ---------------- fused flash attention, S^T formulation ----------------
// S^T = K·Q^T  (C-layout: q = lane&15, key = quad*4+reg) -> per-lane softmax over
// 16 regs + 2 shuffle steps; P roundtrip = 4 ds_write_b64 + 2 ds_read_b128.
__global__ __launch_bounds__(256) void attn_kernel(const unsigned short* __restrict__ qkv,
                                                   const unsigned short* __restrict__ Vt,
                                                   const int* __restrict__ mask_g,
                                                   unsigned short* __restrict__ out) {
    __shared__ __align__(16) unsigned short smP[4][16 * 72];  // per-wave P [q][key], stride 72

    const int t = threadIdx.x;
    const int wave = t >> 6, lane = t & 63;
    const int quad = lane >> 4, l16 = lane & 15;
    const int qt = blockIdx.x, h = blockIdx.y, b = blockIdx.z;
    const int q0 = qt * 64 + wave * 16;       // this wave's 16 q-rows
    const size_t rs = 3 * DMODEL;
    const size_t base = (size_t)b * SEQ * rs;
    const unsigned short* Kp  = qkv + base + DMODEL + h * HDIM;              // [key][d]
    const unsigned short* Vtp = Vt + ((size_t)(b * NHEAD + h)) * HDIM * SEQ; // [d][key]
    const int* mrow = mask_g + b * SEQ;
    unsigned short* smPw = &smP[wave][0];

    // Q B-frag (B[k=d][n=q]): lane n = l16 = q-row, k = quad*8+j
    const unsigned short* Qp = qkv + base + (size_t)(q0 + l16) * rs + h * HDIM + quad * 8;
    s8v qf0 = *(const s8v*)(Qp);
    s8v qf1 = *(const s8v*)(Qp + 32);

    float m_s = -1e30f, l_s = 0.f;   // running max / denom for q-row = l16
    f4v oacc[4] = {};                // O C-layout: row q = quad*4+r, col d = nt*16+l16

    for (int k0 = 0; k0 < SEQ; k0 += 64) {
        // S^T tiles: A = K (lane m = l16 = key), B = Q
        f4v s[4];
        for (int kt4 = 0; kt4 < 4; kt4++) {
            const unsigned short* kr = Kp + (size_t)(k0 + kt4 * 16 + l16) * rs + quad * 8;
            s8v kf0 = *(const s8v*)(kr);
            s8v kf1 = *(const s8v*)(kr + 32);
            f4v z = {};
            z = mfma_bf16(kf0, qf0, z);
            z = mfma_bf16(kf1, qf1, z);
            s[kt4] = z;   // (key = k0 + kt4*16 + quad*4 + r, q = l16)
        }
        // scale + mask (int4: keys kt4*16 + quad*4 .. +3)
        for (int kt4 = 0; kt4 < 4; kt4++) {
            int4 m4 = *(const int4*)&mrow[k0 + kt4 * 16 + quad * 4];
            s[kt4][0] = (m4.x == 0) ? -1e9f : s[kt4][0] * 0.125f;
            s[kt4][1] = (m4.y == 0) ? -1e9f : s[kt4][1] * 0.125f;
            s[kt4][2] = (m4.z == 0) ? -1e9f : s[kt4][2] * 0.125f;
            s[kt4][3] = (m4.w == 0) ? -1e9f : s[kt4][3] * 0.125f;
        }
        // per-lane max over 16 regs, then across quads (xor 16, 32)
        float mx = s[0][0];
        for (int kt4 = 0; kt4 < 4; kt4++)
            for (int r = 0; r < 4; r++) mx = fmaxf(mx, s[kt4][r]);
        mx = fmaxf(mx, __shfl_xor(mx, 16));
        mx = fmaxf(mx, __shfl_xor(mx, 32));
        float nm = fmaxf(m_s, mx);
        float alpha = __expf(m_s - nm);
        m_s = nm;
        // p = exp(s - nm), local sum, reduce across quads
        float lsum = 0.f;
        for (int kt4 = 0; kt4 < 4; kt4++)
            for (int r = 0; r < 4; r++) {
                float p = __expf(s[kt4][r] - nm);
                s[kt4][r] = p;
                lsum += p;
            }
        lsum += __shfl_xor(lsum, 16);
        lsum += __shfl_xor(lsum, 32);
        l_s = l_s * alpha + lsum;
        // rescale O: alpha for q = quad*4+r lives in lane (quad*4+r)
        float alphar[4];
        for (int r = 0; r < 4; r++) alphar[r] = __shfl(alpha, quad * 4 + r);
        for (int nt = 0; nt < 4; nt++)
            for (int r = 0; r < 4; r++) oacc[nt][r] *= alphar[r];
        // P store: lane (l16, quad) writes keys kt4*16+quad*4..+3 of row q=l16 (b64)
        for (int kt4 = 0; kt4 < 4; kt4++) {
            ushort4 pk;
            pk.x = f2b(s[kt4][0]); pk.y = f2b(s[kt4][1]);
            pk.z = f2b(s[kt4][2]); pk.w = f2b(s[kt4][3]);
            *(ushort4*)&smPw[l16 * 72 + kt4 * 16 + quad * 4] = pk;
        }
        // P A-frag (A[m=q=l16][k=key=quad*8+j]) — same wave, no barrier
        s8v pf0 = *(const s8v*)&smPw[l16 * 72 + quad * 8];
        s8v pf1 = *(const s8v*)&smPw[l16 * 72 + quad * 8 + 32];
        // PV: B = Vt (lane n = l16 = d, k = key)
        for (int nt = 0; nt < 4; nt++) {
            const unsigned short* vr = Vtp + (size_t)(nt * 16 + l16) * SEQ + k0 + quad * 8;
            s8v v0 = *(const s8v*)(vr);
            s8v v1 = *(const s8v*)(vr + 32);
            oacc[nt] = mfma_bf16(pf0, v0, oacc[nt]);
            oacc[nt] = mfma_bf16(pf1, v1, oacc[nt]);
        }
    }

    float lrr[4];
    for (int r = 0; r < 4; r++) lrr[r] = __shfl(l_s, quad * 4 + r);
    for (int nt = 0; nt < 4; nt++)
        for (int r = 0; r < 4; r++) {
            int row = q0 + quad * 4 + r;
            int col = h * HDIM + nt * 16 + l16;
            out[((size_t)b * SEQ + row) * DMODEL + col] = f2b(oacc[nt][r] / lrr[r]);
        }
}

extern "C" void kernel_launch(void* const* d_in, const int* in_sizes, int n_in,
                              void* d_out, int out_size, void* d_ws, size_t ws_size,
                              hipStream_t stream) {
    const float* x   = (const float*)d_in[0];
    const int*   msk = (const int*)d_in[1];
    const float* Wq  = (const float*)d_in[2];
    const float* bq  = (const float*)d_in[3];
    const float* Wk  = (const float*)d_in[4];
    const float* bk  = (const float*)d_in[5];
    const float* Wv  = (const float*)d_in[6];
    const float* bv  = (const float*)d_in[7];
    const float* Wo  = (const float*)d_in[8];
    const float* bo  = (const float*)d_in[9];
    const float* W1  = (const float*)d_in[10];
    const float* b1  = (const float*)d_in[11];
    const float* W2  = (const float*)d_in[12];
    const float* b2  = (const float*)d_in[13];
    const float* a1  = (const float*)d_in[14];
    const float* be1 = (const float*)d_in[15];
    const float* a2  = (const float*)d_in[16];
    const float* be2 = (const float*)d_in[17];
    float* outf = (float*)d_out;   // 4096x1024 fp32 = 16 MB

    // ---- arena (peak 58 MB of ws + d_out reuse) ----
    char* ws = (char*)d_ws;
    const size_t MB = 1024 * 1024;
    unsigned short* W1_t   = (unsigned short*)(ws);
    unsigned short* W2_t   = (unsigned short*)(ws + 8 * MB);
    unsigned short* Wqkv_t = (unsigned short*)(ws + 16 * MB);
    float*          bqkv   = (float*)(ws + 22 * MB);
    unsigned short* Vt     = (unsigned short*)(ws + 16 * MB);  // 8MB, lives ph3.5-4
    unsigned short* n2     = (unsigned short*)(ws + 16 * MB);
    unsigned short* Wo_t   = (unsigned short*)(ws + 24 * MB);
    unsigned short* qkvb   = (unsigned short*)(ws + 26 * MB);
    unsigned short* attnO  = (unsigned short*)(ws + 50 * MB);
    unsigned short* ff1    = (unsigned short*)(ws + 26 * MB);
    unsigned short* n1     = (unsigned short*)d_out;
    float*          hbuf   = (float*)d_out;

    // phase 1: weight transposes (fp32 [K,N] -> bf16 [N,K])
    transpose_w<<<dim3(16, 16), 256, 0, stream>>>(Wq, Wqkv_t,               1024, 1024);
    transpose_w<<<dim3(16, 16), 256, 0, stream>>>(Wk, Wqkv_t + 1024 * 1024, 1024, 1024);
    transpose_w<<<dim3(16, 16), 256, 0, stream>>>(Wv, Wqkv_t + 2048 * 1024, 1024, 1024);
    transpose_w<<<dim3(16, 16), 256, 0, stream>>>(Wo, Wo_t,                 1024, 1024);
    transpose_w<<<dim3(16, 64), 256, 0, stream>>>(W1, W1_t, 1024, 4096);
    transpose_w<<<dim3(64, 16), 256, 0, stream>>>(W2, W2_t, 4096, 1024);
    concat_bias<<<12, 256, 0, stream>>>(bq, bk, bv, bqkv);

    // phase 2: n1 = LN1(x)  (bf16, in d_out)
    ln_kernel<<<NTOK, 256, 0, stream>>>(x, a1, be1, n1);
    // phase 3: qkv = n1 @ [Wq|Wk|Wv] + bias  (bf16)
    gemm_bt<false, false, unsigned short><<<dim3(32, 24), 256, 0, stream>>>(
        n1, Wqkv_t, bqkv, nullptr, qkvb, NTOK, 3072, 1024);
    // phase 3.5: Vt = V^T per (b,h)  (over dead Wqkv_t/bqkv)
    transpose_v<<<dim3(32, 16, 2), 256, 0, stream>>>(qkvb, Vt);
    // phase 4: attention (bf16)
    attn_kernel<<<dim3(32, 16, 2), 256, 0, stream>>>(qkvb, Vt, msk, attnO);
    // phase 5: h = x + attnO @ Wo^T + bo  (fp32, into d_out; n1 dead)
    gemm_bt<false, true, float><<<dim3(32, 8), 256, 0, stream>>>(
        attnO, Wo_t, bo, x, hbuf, NTOK, 1024, 1024);
    // phase 6: n2 = LN2(h)  (bf16, over dead Vt)
    ln_kernel<<<NTOK, 256, 0, stream>>>(hbuf, a2, be2, n2);
    // phase 7: ff1 = relu(n2 @ W1 + b1)  (bf16, over dead qkvb/attnO)
    gemm_bt<true, false, unsigned short><<<dim3(32, 32), 256, 0, stream>>>(
        n2, W1_t, b1, nullptr, ff1, NTOK, DFF, 1024);
    // phase 8: out = h + ff1 @ W2 + b2  (fp32; res==C aliasing elementwise-safe)
    gemm_bt<false, true, float><<<dim3(32, 8), 256, 0, stream>>>(
        ff1, W2_t, b2, hbuf, outf, NTOK, DMODEL, DFF);
}

// Round 6
// 460.571 us; speedup vs baseline: 1.3232x; 1.3232x over previous
//
#include <hip/hip_runtime.h>

#define SEQ   2048
#define BATCH 2
#define DMODEL 1024
#define DFF   4096
#define NHEAD 16
#define HDIM  64
#define NTOK  (BATCH*SEQ)   // 4096

typedef short s8v __attribute__((ext_vector_type(8)));
typedef float f4v __attribute__((ext_vector_type(4)));

__device__ __forceinline__ float b2f(unsigned short u) {
    union { unsigned int i; float f; } v; v.i = ((unsigned int)u) << 16; return v.f;
}
__device__ __forceinline__ unsigned short f2b(float f) {
    union { unsigned int i; float f; } v; v.f = f;
    unsigned int r = v.i + 0x7FFFu + ((v.i >> 16) & 1u);
    return (unsigned short)(r >> 16);
}

__device__ __forceinline__ f4v mfma_bf16(s8v a, s8v b, f4v c) {
    return __builtin_amdgcn_mfma_f32_16x16x32_bf16(a, b, c, 0, 0, 0);
}

__device__ __forceinline__ void gload_lds16(const void* g, void* l) {
    __builtin_amdgcn_global_load_lds(
        (const __attribute__((address_space(1))) unsigned int*)g,
        (__attribute__((address_space(3))) unsigned int*)l, 16, 0, 0);
}

// ---------------- transpose + fp32->bf16: src [R,C] f32 -> dst [C,R] bf16 ----------------
__global__ __launch_bounds__(256) void transpose_w(const float* __restrict__ src,
                                                   unsigned short* __restrict__ dst,
                                                   int R, int C) {
    __shared__ unsigned short tl[64 * 65];
    const int t = threadIdx.x;
    const int br = blockIdx.x, bc = blockIdx.y;
    for (int i = 0; i < 16; i++) {
        int idx = t + 256 * i;
        int r = idx >> 6, c = idx & 63;
        tl[r * 65 + c] = f2b(src[(size_t)(br * 64 + r) * C + bc * 64 + c]);
    }
    __syncthreads();
    for (int i = 0; i < 16; i++) {
        int idx = t + 256 * i;
        int r2 = idx >> 6, c2 = idx & 63;
        dst[(size_t)(bc * 64 + r2) * R + br * 64 + c2] = tl[c2 * 65 + r2];
    }
}

// ---------------- pack K: qkv K-part -> Kc [b][h][kt][swizzled 64x64 tile] ----------------
// tile row r = key (local), 16B phys chunk cp holds logical d-chunk cl = cp ^ (r&7)
__global__ __launch_bounds__(256) void pack_k(const unsigned short* __restrict__ qkv,
                                              unsigned short* __restrict__ Kc) {
    const int t = threadIdx.x;
    const int kt = blockIdx.x, h = blockIdx.y, b = blockIdx.z;
    const size_t rs = 3 * DMODEL;
    const unsigned short* src = qkv + (size_t)b * SEQ * rs + DMODEL + h * HDIM;
    unsigned short* dst = Kc + ((size_t)((b * NHEAD + h) * 32 + kt)) * 4096;
    for (int i = 0; i < 2; i++) {
        int ci = t + 256 * i;            // chunk 0..511
        int r = ci >> 3, cp = ci & 7;
        int cl = cp ^ (r & 7);
        *(uint4*)&dst[ci * 8] = *(const uint4*)&src[(size_t)(kt * 64 + r) * rs + cl * 8];
    }
}

// ---------------- pack V: qkv V-part [key][d] -> Vc [b][h][kt][swizzled [d][key] tile] ---
// tile row r = d, phys chunk cp holds logical key-chunk cl = cp ^ (r&7) (keys cl*8..+7)
__global__ __launch_bounds__(256) void pack_v(const unsigned short* __restrict__ qkv,
                                              unsigned short* __restrict__ Vc) {
    __shared__ unsigned short tl[64 * 65];
    const int t = threadIdx.x;
    const int kt = blockIdx.x, h = blockIdx.y, b = blockIdx.z;
    const size_t rs = 3 * DMODEL;
    const size_t src0 = (size_t)b * SEQ * rs + 2 * DMODEL + h * HDIM;
    for (int i = 0; i < 16; i++) {
        int idx = t + 256 * i;
        int r = idx >> 6, c = idx & 63;      // r = key local, c = d
        tl[r * 65 + c] = qkv[src0 + (size_t)(kt * 64 + r) * rs + c];
    }
    __syncthreads();
    unsigned short* dst = Vc + ((size_t)((b * NHEAD + h) * 32 + kt)) * 4096;
    for (int i = 0; i < 2; i++) {
        int ci = t + 256 * i;
        int r = ci >> 3, cp = ci & 7;        // r = d
        int cl = cp ^ (r & 7);
        ushort4 e0, e1;
        e0.x = tl[(cl * 8 + 0) * 65 + r]; e0.y = tl[(cl * 8 + 1) * 65 + r];
        e0.z = tl[(cl * 8 + 2) * 65 + r]; e0.w = tl[(cl * 8 + 3) * 65 + r];
        e1.x = tl[(cl * 8 + 4) * 65 + r]; e1.y = tl[(cl * 8 + 5) * 65 + r];
        e1.z = tl[(cl * 8 + 6) * 65 + r]; e1.w = tl[(cl * 8 + 7) * 65 + r];
        *(ushort4*)&dst[ci * 8]     = e0;
        *(ushort4*)&dst[ci * 8 + 4] = e1;
    }
}

// ---------------- concat qkv bias (fp32) ----------------
__global__ __launch_bounds__(256) void concat_bias(const float* bq, const float* bk,
                                                   const float* bv, float* o) {
    int t = blockIdx.x * 256 + threadIdx.x;
    if (t < 1024) o[t] = bq[t];
    else if (t < 2048) o[t] = bk[t - 1024];
    else if (t < 3072) o[t] = bv[t - 2048];
}

// ---------------- layernorm fp32 in -> bf16 out (torch: ddof=1, eps on std) ----------------
__global__ __launch_bounds__(256) void ln_kernel(const float* __restrict__ x,
                                                 const float* __restrict__ al,
                                                 const float* __restrict__ be,
                                                 unsigned short* __restrict__ o) {
    const int row = blockIdx.x;
    const float* xr = x + (size_t)row * DMODEL;
    float4 u = ((const float4*)xr)[threadIdx.x];
    float v[4] = { u.x, u.y, u.z, u.w };
    float s = v[0] + v[1] + v[2] + v[3];
    float sq = v[0]*v[0] + v[1]*v[1] + v[2]*v[2] + v[3]*v[3];
    for (int off = 32; off; off >>= 1) { s += __shfl_xor(s, off); sq += __shfl_xor(sq, off); }
    __shared__ float red[8];
    int wave = threadIdx.x >> 6, lane = threadIdx.x & 63;
    if (!lane) { red[wave] = s; red[4 + wave] = sq; }
    __syncthreads();
    s = red[0] + red[1] + red[2] + red[3];
    sq = red[4] + red[5] + red[6] + red[7];
    float mean = s * (1.f / DMODEL);
    float var = (sq - (float)DMODEL * mean * mean) * (1.f / (DMODEL - 1));
    var = var < 0.f ? 0.f : var;
    float inv = al[0] / (sqrtf(var) + 1e-6f);
    float bt = be[0];
    uint2 ou;
    unsigned short r0 = f2b((v[0] - mean) * inv + bt);
    unsigned short r1 = f2b((v[1] - mean) * inv + bt);
    unsigned short r2 = f2b((v[2] - mean) * inv + bt);
    unsigned short r3 = f2b((v[3] - mean) * inv + bt);
    ou.x = (unsigned int)r0 | ((unsigned int)r1 << 16);
    ou.y = (unsigned int)r2 | ((unsigned int)r3 << 16);
    ((uint2*)(o + (size_t)row * DMODEL))[threadIdx.x] = ou;
}

// ---------------- m97-style GEMM: C = [relu](A @ Bt^T + bias) [+ res] ----------------
template<bool RELU, bool RES, typename CT>
__global__ __launch_bounds__(256) void gemm_bt(const unsigned short* __restrict__ A,
                                               const unsigned short* __restrict__ Bt,
                                               const float* __restrict__ bias,
                                               const float* __restrict__ res,
                                               CT* __restrict__ C,
                                               int M, int N, int K) {
    __shared__ __align__(16) unsigned short smA[128 * 32];
    __shared__ __align__(16) unsigned short smB[128 * 32];
    const int t = threadIdx.x;
    const int wave = t >> 6, lane = t & 63;
    const int quad = lane >> 4, l16 = lane & 15;
    const int wm = wave & 1, wn = wave >> 1;
    const int m0 = blockIdx.x * 128, n0 = blockIdx.y * 128;

    f4v acc[4][4] = {};

    const int c0 = t, c1 = t + 256;
    const int rA0 = c0 >> 2, sA0 = c0 & 3;
    const int rA1 = c1 >> 2, sA1 = c1 & 3;

    for (int k0 = 0; k0 < K; k0 += 32) {
        __syncthreads();
        gload_lds16(A  + (size_t)(m0 + rA0) * K + k0 + sA0 * 8, smA + c0 * 8);
        gload_lds16(A  + (size_t)(m0 + rA1) * K + k0 + sA1 * 8, smA + c1 * 8);
        gload_lds16(Bt + (size_t)(n0 + rA0) * K + k0 + sA0 * 8, smB + c0 * 8);
        gload_lds16(Bt + (size_t)(n0 + rA1) * K + k0 + sA1 * 8, smB + c1 * 8);
        __syncthreads();
        s8v a[4], b[4];
        for (int i = 0; i < 4; i++)
            a[i] = *(const s8v*)&smA[(wm * 64 + i * 16 + l16) * 32 + quad * 8];
        for (int i = 0; i < 4; i++)
            b[i] = *(const s8v*)&smB[(wn * 64 + i * 16 + l16) * 32 + quad * 8];
        for (int mi = 0; mi < 4; mi++)
            for (int ni = 0; ni < 4; ni++)
                acc[mi][ni] = mfma_bf16(a[mi], b[ni], acc[mi][ni]);
    }

    for (int mi = 0; mi < 4; mi++) {
        for (int ni = 0; ni < 4; ni++) {
            int col = n0 + wn * 64 + ni * 16 + l16;
            float bv = bias[col];
            for (int r = 0; r < 4; r++) {
                int row = m0 + wm * 64 + mi * 16 + quad * 4 + r;
                float v = acc[mi][ni][r] + bv;
                if (RELU) v = v > 0.f ? v : 0.f;
                if (RES) v += res[(size_t)row * N + col];
                if constexpr (sizeof(CT) == 2)
                    C[(size_t)row * N + col] = f2b(v);
                else
                    C[(size_t)row * N + col] = v;
            }
        }
    }
}

// ---------------- fused flash attention: LDS-staged swizzled K/V tiles, S^T softmax ------
__global__ __launch_bounds__(256) void attn_kernel(const unsigned short* __restrict__ qkv,
                                                   const unsigned short* __restrict__ Kc,
                                                   const unsigned short* __restrict__ Vc,
                                                   const int* __restrict__ mask_g,
                                                   unsigned short* __restrict__ out) {
    __shared__ __align__(16) unsigned short smK[4096];        // 64 keys x 64 d, swizzled
    __shared__ __align__(16) unsigned short smV[4096];        // 64 d x 64 keys, swizzled
    __shared__ __align__(16) unsigned short smP[4][16 * 72];  // per-wave P [q][key]

    const int t = threadIdx.x;
    const int wave = t >> 6, lane = t & 63;
    const int quad = lane >> 4, l16 = lane & 15;
    const int qt = blockIdx.x, h = blockIdx.y, b = blockIdx.z;
    const int q0 = qt * 64 + wave * 16;
    const size_t rs = 3 * DMODEL;
    const size_t base = (size_t)b * SEQ * rs;
    const unsigned short* Kbh = Kc + ((size_t)(b * NHEAD + h)) * 32 * 4096;
    const unsigned short* Vbh = Vc + ((size_t)(b * NHEAD + h)) * 32 * 4096;
    const int* mrow = mask_g + b * SEQ;
    unsigned short* smPw = &smP[wave][0];

    // Q B-frag (B[k=d][n=q]): lane n = l16 = q-row, k = quad*8+j (one-time divergent load)
    const unsigned short* Qp = qkv + base + (size_t)(q0 + l16) * rs + h * HDIM + quad * 8;
    s8v qf0 = *(const s8v*)(Qp);
    s8v qf1 = *(const s8v*)(Qp + 32);

    float m_s = -1e30f, l_s = 0.f;   // running max / denom for q-row = l16
    f4v oacc[4] = {};                // O C-layout: row q = quad*4+r, col d = nt*16+l16

    for (int kt = 0; kt < 32; kt++) {
        const int k0 = kt * 64;
        const unsigned short* ks = Kbh + kt * 4096;
        const unsigned short* vs = Vbh + kt * 4096;
        __syncthreads();
        gload_lds16(ks + t * 8,           smK + t * 8);
        gload_lds16(ks + (t + 256) * 8,   smK + (t + 256) * 8);
        gload_lds16(vs + t * 8,           smV + t * 8);
        gload_lds16(vs + (t + 256) * 8,   smV + (t + 256) * 8);
        __syncthreads();

        // S^T tiles: A = K frag (m = key = l16 within group), B = Q
        f4v s[4];
        for (int kt4 = 0; kt4 < 4; kt4++) {
            int r = kt4 * 16 + l16, sw = r & 7;
            s8v kf0 = *(const s8v*)&smK[r * 64 + ((quad ^ sw) * 8)];
            s8v kf1 = *(const s8v*)&smK[r * 64 + (((quad + 4) ^ sw) * 8)];
            f4v z = {};
            z = mfma_bf16(kf0, qf0, z);
            z = mfma_bf16(kf1, qf1, z);
            s[kt4] = z;   // (key = k0 + kt4*16 + quad*4 + r, q = l16)
        }
        // scale + mask
        for (int kt4 = 0; kt4 < 4; kt4++) {
            int4 m4 = *(const int4*)&mrow[k0 + kt4 * 16 + quad * 4];
            s[kt4][0] = (m4.x == 0) ? -1e9f : s[kt4][0] * 0.125f;
            s[kt4][1] = (m4.y == 0) ? -1e9f : s[kt4][1] * 0.125f;
            s[kt4][2] = (m4.z == 0) ? -1e9f : s[kt4][2] * 0.125f;
            s[kt4][3] = (m4.w == 0) ? -1e9f : s[kt4][3] * 0.125f;
        }
        // per-lane max over 16 regs, then across quads (xor 16, 32)
        float mx = s[0][0];
        for (int kt4 = 0; kt4 < 4; kt4++)
            for (int r = 0; r < 4; r++) mx = fmaxf(mx, s[kt4][r]);
        mx = fmaxf(mx, __shfl_xor(mx, 16));
        mx = fmaxf(mx, __shfl_xor(mx, 32));
        float nm = fmaxf(m_s, mx);
        float alpha = __expf(m_s - nm);
        m_s = nm;
        float lsum = 0.f;
        for (int kt4 = 0; kt4 < 4; kt4++)
            for (int r = 0; r < 4; r++) {
                float p = __expf(s[kt4][r] - nm);
                s[kt4][r] = p;
                lsum += p;
            }
        lsum += __shfl_xor(lsum, 16);
        lsum += __shfl_xor(lsum, 32);
        l_s = l_s * alpha + lsum;
        // rescale O: alpha for q = quad*4+r lives in lane (quad*4+r)
        float alphar[4];
        for (int r = 0; r < 4; r++) alphar[r] = __shfl(alpha, quad * 4 + r);
        for (int nt = 0; nt < 4; nt++)
            for (int r = 0; r < 4; r++) oacc[nt][r] *= alphar[r];
        // P store: lane (l16, quad) writes keys kt4*16+quad*4..+3 of row q=l16 (b64)
        for (int kt4 = 0; kt4 < 4; kt4++) {
            ushort4 pk;
            pk.x = f2b(s[kt4][0]); pk.y = f2b(s[kt4][1]);
            pk.z = f2b(s[kt4][2]); pk.w = f2b(s[kt4][3]);
            *(ushort4*)&smPw[l16 * 72 + kt4 * 16 + quad * 4] = pk;
        }
        // P A-frag (A[m=q=l16][k=key=quad*8+j]) — same wave, no barrier
        s8v pf0 = *(const s8v*)&smPw[l16 * 72 + quad * 8];
        s8v pf1 = *(const s8v*)&smPw[l16 * 72 + quad * 8 + 32];
        // PV: B = V frag from smV (row d = nt*16+l16, key chunk quad / quad+4, swizzled)
        for (int nt = 0; nt < 4; nt++) {
            int r = nt * 16 + l16, sw = r & 7;
            s8v v0 = *(const s8v*)&smV[r * 64 + ((quad ^ sw) * 8)];
            s8v v1 = *(const s8v*)&smV[r * 64 + (((quad + 4) ^ sw) * 8)];
            oacc[nt] = mfma_bf16(pf0, v0, oacc[nt]);
            oacc[nt] = mfma_bf16(pf1, v1, oacc[nt]);
        }
    }

    float lrr[4];
    for (int r = 0; r < 4; r++) lrr[r] = __shfl(l_s, quad * 4 + r);
    for (int nt = 0; nt < 4; nt++)
        for (int r = 0; r < 4; r++) {
            int row = q0 + quad * 4 + r;
            int col = h * HDIM + nt * 16 + l16;
            out[((size_t)b * SEQ + row) * DMODEL + col] = f2b(oacc[nt][r] / lrr[r]);
        }
}

extern "C" void kernel_launch(void* const* d_in, const int* in_sizes, int n_in,
                              void* d_out, int out_size, void* d_ws, size_t ws_size,
                              hipStream_t stream) {
    const float* x   = (const float*)d_in[0];
    const int*   msk = (const int*)d_in[1];
    const float* Wq  = (const float*)d_in[2];
    const float* bq  = (const float*)d_in[3];
    const float* Wk  = (const float*)d_in[4];
    const float* bk  = (const float*)d_in[5];
    const float* Wv  = (const float*)d_in[6];
    const float* bv  = (const float*)d_in[7];
    const float* Wo  = (const float*)d_in[8];
    const float* bo  = (const float*)d_in[9];
    const float* W1  = (const float*)d_in[10];
    const float* b1  = (const float*)d_in[11];
    const float* W2  = (const float*)d_in[12];
    const float* b2  = (const float*)d_in[13];
    const float* a1  = (const float*)d_in[14];
    const float* be1 = (const float*)d_in[15];
    const float* a2  = (const float*)d_in[16];
    const float* be2 = (const float*)d_in[17];
    float* outf = (float*)d_out;   // 4096x1024 fp32 = 16 MB

    // ---- arena (peak 58 MB of ws + d_out reuse) ----
    // ws[ 0, 8)MB : W1_t (ph1-7)
    // ws[ 8,16)MB : W2_t (ph1-8)
    // ws[16,22)MB : Wqkv_t (ph1-3) -> Kc 8MB [16,24) (ph3.5-4) -> n2 [16,24) (ph6-7)
    // ws[22,24)MB : bqkv (ph1-3)
    // ws[24,26)MB : Wo_t (ph1-5)
    // ws[26,58)MB : qkvb 24MB (ph3-4) + attnO 8MB @+24 (ph4-5) -> ff1 32MB (ph7-8)
    // d_out 16MB  : n1 bf16 (ph2-3) -> Vc bf16 [0,8) (ph3.5-4) -> h fp32 (ph5-8)
    char* ws = (char*)d_ws;
    const size_t MB = 1024 * 1024;
    unsigned short* W1_t   = (unsigned short*)(ws);
    unsigned short* W2_t   = (unsigned short*)(ws + 8 * MB);
    unsigned short* Wqkv_t = (unsigned short*)(ws + 16 * MB);
    float*          bqkv   = (float*)(ws + 22 * MB);
    unsigned short* Kc     = (unsigned short*)(ws + 16 * MB);
    unsigned short* n2     = (unsigned short*)(ws + 16 * MB);
    unsigned short* Wo_t   = (unsigned short*)(ws + 24 * MB);
    unsigned short* qkvb   = (unsigned short*)(ws + 26 * MB);
    unsigned short* attnO  = (unsigned short*)(ws + 50 * MB);
    unsigned short* ff1    = (unsigned short*)(ws + 26 * MB);
    unsigned short* n1     = (unsigned short*)d_out;
    unsigned short* Vc     = (unsigned short*)d_out;
    float*          hbuf   = (float*)d_out;

    // phase 1: weight transposes (fp32 [K,N] -> bf16 [N,K])
    transpose_w<<<dim3(16, 16), 256, 0, stream>>>(Wq, Wqkv_t,               1024, 1024);
    transpose_w<<<dim3(16, 16), 256, 0, stream>>>(Wk, Wqkv_t + 1024 * 1024, 1024, 1024);
    transpose_w<<<dim3(16, 16), 256, 0, stream>>>(Wv, Wqkv_t + 2048 * 1024, 1024, 1024);
    transpose_w<<<dim3(16, 16), 256, 0, stream>>>(Wo, Wo_t,                 1024, 1024);
    transpose_w<<<dim3(16, 64), 256, 0, stream>>>(W1, W1_t, 1024, 4096);
    transpose_w<<<dim3(64, 16), 256, 0, stream>>>(W2, W2_t, 4096, 1024);
    concat_bias<<<12, 256, 0, stream>>>(bq, bk, bv, bqkv);

    // phase 2: n1 = LN1(x)  (bf16, in d_out)
    ln_kernel<<<NTOK, 256, 0, stream>>>(x, a1, be1, n1);
    // phase 3: qkv = n1 @ [Wq|Wk|Wv] + bias  (bf16)
    gemm_bt<false, false, unsigned short><<<dim3(32, 24), 256, 0, stream>>>(
        n1, Wqkv_t, bqkv, nullptr, qkvb, NTOK, 3072, 1024);
    // phase 3.5: pack K (over dead Wqkv_t) and V (over dead n1 in d_out), swizzled tiles
    pack_k<<<dim3(32, 16, 2), 256, 0, stream>>>(qkvb, Kc);
    pack_v<<<dim3(32, 16, 2), 256, 0, stream>>>(qkvb, Vc);
    // phase 4: attention
    attn_kernel<<<dim3(32, 16, 2), 256, 0, stream>>>(qkvb, Kc, Vc, msk, attnO);
    // phase 5: h = x + attnO @ Wo^T + bo  (fp32, into d_out; Vc dead)
    gemm_bt<false, true, float><<<dim3(32, 8), 256, 0, stream>>>(
        attnO, Wo_t, bo, x, hbuf, NTOK, 1024, 1024);
    // phase 6: n2 = LN2(h)  (bf16, over dead Kc)
    ln_kernel<<<NTOK, 256, 0, stream>>>(hbuf, a2, be2, n2);
    // phase 7: ff1 = relu(n2 @ W1 + b1)  (bf16, over dead qkvb/attnO)
    gemm_bt<true, false, unsigned short><<<dim3(32, 32), 256, 0, stream>>>(
        n2, W1_t, b1, nullptr, ff1, NTOK, DFF, 1024);
    // phase 8: out = h + ff1 @ W2 + b2  (fp32; res==C aliasing elementwise-safe)
    gemm_bt<false, true, float><<<dim3(32, 8), 256, 0, stream>>>(
        ff1, W2_t, b2, hbuf, outf, NTOK, DMODEL, DFF);
}